// Round 3
// baseline (468.497 us; speedup 1.0000x reference)
//
#include <hip/hip_runtime.h>

// MLPPredictor, round 9. r8 established:
//  - dur_us includes ~372us of harness re-poison fills (2 x 1.2GB
//    fillBufferAligned @ ~185us, 82% HBM peak, size independent of our ws
//    usage) -> controllable kernel slice is only ~87us.
//  - linearity split works: score[e] = P1[src] + P2[dst] + eh·W3^T, with
//    P1[n]=h[n]·W1^T+b, P2[n]=h[n]·W2^T precomputed (N x 16f rows, 64B
//    lines, 12.8MB total, L2-resident). Per-edge gather = 2 x 64B lines.
// r9 trims the overhead around the irreducible streams (eh 307MB + out
// 24MB + src/dst 9.6MB ~ 54us; ptab 64MB ~ 11us):
//  - build_wfrag kernel deleted; W-fragments built inline per-lane from
//    Ww (15KB, L2-hit) in both kernels. One less launch + dependency.
//  - 256-thread blocks (4 waves): main 9375->2344 blocks, ptab ->1563.
//  - 32-bit index math (all element offsets < 2^31).

typedef __attribute__((ext_vector_type(8))) short short8;
typedef __attribute__((ext_vector_type(4))) float f32x4;

#define NC      10
#define TPW     4            // 16-edge tiles per wave
#define PSTRIDE 16           // floats per P-table row (64 B, one line)

__device__ __forceinline__ unsigned short f2bf(float f) {
    unsigned u = __builtin_bit_cast(unsigned, f);
    u += 0x7FFFu + ((u >> 16) & 1u);          // round-to-nearest-even
    return (unsigned short)(u >> 16);
}

__device__ __forceinline__ short8 cvt8(f32x4 a, f32x4 b) {
    short8 s;
    s[0]=(short)f2bf(a[0]); s[1]=(short)f2bf(a[1]);
    s[2]=(short)f2bf(a[2]); s[3]=(short)f2bf(a[3]);
    s[4]=(short)f2bf(b[0]); s[5]=(short)f2bf(b[1]);
    s[6]=(short)f2bf(b[2]); s[7]=(short)f2bf(b[3]);
    return s;
}

// B-fragment for MFMA step t (k = t*32 + q*8 + j), built from Ww in-regs.
// Ww is 10x384 f32 (15 KB) -> L1/L2-hit after first touch.
__device__ __forceinline__ short8 wfrag(const float* __restrict__ Ww,
                                        int t, int n, int q) {
    short8 b = (short8)0;
    if (n < NC) {
        const float* w = Ww + n * 384 + t * 32 + q * 8;
        b = cvt8(*(const f32x4*)w, *(const f32x4*)(w + 4));
    }
    return b;
}

#define LGF(v0,v1,v2,v3,v4,v5,v6,v7,p)          \
    v0 = *(const f32x4*)((p) + 0);              \
    v1 = *(const f32x4*)((p) + 4);              \
    v2 = *(const f32x4*)((p) + 32);             \
    v3 = *(const f32x4*)((p) + 36);             \
    v4 = *(const f32x4*)((p) + 64);             \
    v5 = *(const f32x4*)((p) + 68);             \
    v6 = *(const f32x4*)((p) + 96);             \
    v7 = *(const f32x4*)((p) + 100);

// ---- prep: per-node partials. 16 nodes/wave, 64/block, coalesced h. ----
// P1[n][c] = h[n]·W1^T[c] + b[c];  P2[n][c] = h[n]·W2^T[c].
__global__ __launch_bounds__(256) void build_ptab(
    const float* __restrict__ h, const float* __restrict__ Ww,
    const float* __restrict__ Wb, float* __restrict__ P1,
    float* __restrict__ P2, int N)
{
    const int l = threadIdx.x & 63;
    const int w = threadIdx.x >> 6;
    const int n = l & 15;
    const int q = l >> 4;

    short8 bf[8];
#pragma unroll
    for (int t = 0; t < 8; ++t) bf[t] = wfrag(Ww, t, n, q);
    const float bias = (n < NC) ? Wb[n] : 0.f;

    const int base = blockIdx.x * 64 + w * 16;
    const int node = base + n;
    const int ndc = (node < N) ? node : (N - 1);
    const float* ph = h + ndc * 128 + q * 8;

    f32x4 x0,x1,x2,x3,x4,x5,x6,x7;
    LGF(x0,x1,x2,x3,x4,x5,x6,x7, ph)
    const short8 a0 = cvt8(x0,x1), a1 = cvt8(x2,x3);
    const short8 a2 = cvt8(x4,x5), a3 = cvt8(x6,x7);

    f32x4 acc1 = {0.f,0.f,0.f,0.f}, acc2 = {0.f,0.f,0.f,0.f};
    acc1 = __builtin_amdgcn_mfma_f32_16x16x32_bf16(a0, bf[0], acc1, 0,0,0);
    acc1 = __builtin_amdgcn_mfma_f32_16x16x32_bf16(a1, bf[1], acc1, 0,0,0);
    acc1 = __builtin_amdgcn_mfma_f32_16x16x32_bf16(a2, bf[2], acc1, 0,0,0);
    acc1 = __builtin_amdgcn_mfma_f32_16x16x32_bf16(a3, bf[3], acc1, 0,0,0);
    acc2 = __builtin_amdgcn_mfma_f32_16x16x32_bf16(a0, bf[4], acc2, 0,0,0);
    acc2 = __builtin_amdgcn_mfma_f32_16x16x32_bf16(a1, bf[5], acc2, 0,0,0);
    acc2 = __builtin_amdgcn_mfma_f32_16x16x32_bf16(a2, bf[6], acc2, 0,0,0);
    acc2 = __builtin_amdgcn_mfma_f32_16x16x32_bf16(a3, bf[7], acc2, 0,0,0);

    // C/D: col = n (class), row(node-in-tile) = q*4 + r
#pragma unroll
    for (int r = 0; r < 4; ++r) {
        const int nd = base + q * 4 + r;
        if (nd < N) {
            P1[nd * PSTRIDE + n] = acc1[r] + bias;
            P2[nd * PSTRIDE + n] = acc2[r];
        }
    }
}

// ---- main: out[e] = eh[e]·W3^T (MFMA) + P1[src[e]] + P2[dst[e]] ----
__global__ __launch_bounds__(256, 4) void mlp_edge_fused(
    const float* __restrict__ eh,            // [E,128] f32 stream
    const float* __restrict__ Ww,            // [10,384]
    const float* __restrict__ P1,            // [N,PSTRIDE]
    const float* __restrict__ P2,            // [N,PSTRIDE]
    const int*   __restrict__ src,
    const int*   __restrict__ dst,
    float* __restrict__ out,                 // [E,10]
    int E)
{
    const int l = threadIdx.x & 63;
    const int w = threadIdx.x >> 6;
    const int n = l & 15;             // A-row (edge-in-tile) AND B-col (class)
    const int q = l >> 4;             // k-quad

    const short8 bf0 = wfrag(Ww,  8, n, q);
    const short8 bf1 = wfrag(Ww,  9, n, q);
    const short8 bf2 = wfrag(Ww, 10, n, q);
    const short8 bf3 = wfrag(Ww, 11, n, q);
    const int cn = (n < NC) ? n : 0;

    const int tile0 = blockIdx.x * 16 + w * TPW;   // 16-edge tiles

#pragma unroll 1
    for (int tt = 0; tt < TPW; ++tt) {
        const int base = (tile0 + tt) * 16;
        if (base >= E) break;                       // wave-uniform
        const int e  = base + n;
        const int ec = (e < E) ? e : (E - 1);
        const float* pe = eh + (size_t)ec * 128 + q * 8;

        // issue the long-latency eh stream first
        f32x4 z0,z1,z2,z3,z4,z5,z6,z7;
        LGF(z0,z1,z2,z3,z4,z5,z6,z7, pe)

        // epilogue operands: this lane's 4 output edges are base + q*4 + r.
        // Per q-group all 16 lanes hit the same 64B P-row -> 4 lines/instr.
        int s2[4], d2[4];
#pragma unroll
        for (int r = 0; r < 4; ++r) {
            const int e2  = base + q * 4 + r;
            const int e2c = (e2 < E) ? e2 : (E - 1);
            s2[r] = src[e2c];
            d2[r] = dst[e2c];
        }
        float pv1[4], pv2[4];
#pragma unroll
        for (int r = 0; r < 4; ++r) {
            pv1[r] = P1[s2[r] * PSTRIDE + cn];
            pv2[r] = P2[d2[r] * PSTRIDE + cn];
        }

        f32x4 acc = {0.f, 0.f, 0.f, 0.f};
        acc = __builtin_amdgcn_mfma_f32_16x16x32_bf16(cvt8(z0,z1), bf0, acc, 0,0,0);
        acc = __builtin_amdgcn_mfma_f32_16x16x32_bf16(cvt8(z2,z3), bf1, acc, 0,0,0);
        acc = __builtin_amdgcn_mfma_f32_16x16x32_bf16(cvt8(z4,z5), bf2, acc, 0,0,0);
        acc = __builtin_amdgcn_mfma_f32_16x16x32_bf16(cvt8(z6,z7), bf3, acc, 0,0,0);

        // C/D: col = n (class), row(edge-in-tile) = q*4 + r
        if (n < NC) {
#pragma unroll
            for (int r = 0; r < 4; ++r) {
                const int e2 = base + q * 4 + r;
                if (e2 < E) out[(size_t)e2 * NC + n] = acc[r] + pv1[r] + pv2[r];
            }
        }
    }
}

// ---- fallback (ws too small): full-K f32-gather kernel ----
__global__ __launch_bounds__(64, 3) void mlp_edge_f32(
    const float* __restrict__ h, const float* __restrict__ eh,
    const float* __restrict__ Ww, const float* __restrict__ Wb,
    const int* __restrict__ src, const int* __restrict__ dst,
    float* __restrict__ out, int E)
{
    const int l = threadIdx.x;
    const int n = l & 15;
    const int q = l >> 4;

    short8 bf[12];
#pragma unroll
    for (int t = 0; t < 12; ++t) bf[t] = wfrag(Ww, t, n, q);
    const float bias = (n < NC) ? Wb[n] : 0.f;

    const int tile0 = blockIdx.x * TPW;

#pragma unroll 1
    for (int tt = 0; tt < TPW; ++tt) {
        const int base = (tile0 + tt) * 16;
        if (base >= E) break;
        const int e  = base + n;
        const int ec = (e < E) ? e : (E - 1);
        const int  sA = src[ec];
        const int  dA = dst[ec];
        const float* pe = eh + (size_t)ec * 128 + q * 8;
        const float* ps = h + (size_t)sA * 128 + q * 8;
        const float* pd = h + (size_t)dA * 128 + q * 8;

        f32x4 x0,x1,x2,x3,x4,x5,x6,x7;
        f32x4 y0,y1,y2,y3,y4,y5,y6,y7;
        f32x4 z0,z1,z2,z3,z4,z5,z6,z7;
        LGF(x0,x1,x2,x3,x4,x5,x6,x7, ps)
        LGF(y0,y1,y2,y3,y4,y5,y6,y7, pd)
        LGF(z0,z1,z2,z3,z4,z5,z6,z7, pe)

        f32x4 acc = {0.f, 0.f, 0.f, 0.f};
        acc = __builtin_amdgcn_mfma_f32_16x16x32_bf16(cvt8(x0,x1), bf[0], acc, 0,0,0);
        acc = __builtin_amdgcn_mfma_f32_16x16x32_bf16(cvt8(x2,x3), bf[1], acc, 0,0,0);
        acc = __builtin_amdgcn_mfma_f32_16x16x32_bf16(cvt8(x4,x5), bf[2], acc, 0,0,0);
        acc = __builtin_amdgcn_mfma_f32_16x16x32_bf16(cvt8(x6,x7), bf[3], acc, 0,0,0);
        acc = __builtin_amdgcn_mfma_f32_16x16x32_bf16(cvt8(y0,y1), bf[4], acc, 0,0,0);
        acc = __builtin_amdgcn_mfma_f32_16x16x32_bf16(cvt8(y2,y3), bf[5], acc, 0,0,0);
        acc = __builtin_amdgcn_mfma_f32_16x16x32_bf16(cvt8(y4,y5), bf[6], acc, 0,0,0);
        acc = __builtin_amdgcn_mfma_f32_16x16x32_bf16(cvt8(y6,y7), bf[7], acc, 0,0,0);
        acc = __builtin_amdgcn_mfma_f32_16x16x32_bf16(cvt8(z0,z1), bf[8],  acc, 0,0,0);
        acc = __builtin_amdgcn_mfma_f32_16x16x32_bf16(cvt8(z2,z3), bf[9],  acc, 0,0,0);
        acc = __builtin_amdgcn_mfma_f32_16x16x32_bf16(cvt8(z4,z5), bf[10], acc, 0,0,0);
        acc = __builtin_amdgcn_mfma_f32_16x16x32_bf16(cvt8(z6,z7), bf[11], acc, 0,0,0);

        if (n < NC) {
#pragma unroll
            for (int r = 0; r < 4; ++r) {
                const int e2 = base + q * 4 + r;
                if (e2 < E) out[(size_t)e2 * NC + n] = acc[r] + bias;
            }
        }
    }
}

extern "C" void kernel_launch(void* const* d_in, const int* in_sizes, int n_in,
                              void* d_out, int out_size, void* d_ws, size_t ws_size,
                              hipStream_t stream) {
    const float* h   = (const float*)d_in[0];
    const float* eh  = (const float*)d_in[1];
    const float* Ww  = (const float*)d_in[2];
    const float* Wb  = (const float*)d_in[3];
    const int*   src = (const int*)d_in[4];
    const int*   dst = (const int*)d_in[5];
    float* out = (float*)d_out;

    const int E    = in_sizes[4];
    const int N128 = in_sizes[0];                  // N * 128 elements of h
    const int N    = N128 / 128;

    const size_t pfloats = (size_t)N * PSTRIDE;    // per table
    const size_t need = 2 * pfloats * sizeof(float);

    if (ws_size >= need) {
        float* P1 = (float*)d_ws;
        float* P2 = P1 + pfloats;
        build_ptab<<<(N + 63) / 64, 256, 0, stream>>>(h, Ww, Wb, P1, P2, N);
        // 256 edges per block (4 waves x TPW x 16)
        const int blocks = (E + 255) / 256;
        mlp_edge_fused<<<blocks, 256, 0, stream>>>(eh, Ww, P1, P2, src, dst, out, E);
    } else {
        const int blocks = (E + 16 * TPW - 1) / (16 * TPW);
        mlp_edge_f32<<<blocks, 64, 0, stream>>>(h, eh, Ww, Wb, src, dst, out, E);
    }
}